// Round 14
// baseline (283.512 us; speedup 1.0000x reference)
//
#include <hip/hip_runtime.h>

#define DM   2048
#define SEQ  2048
#define NB   2
#define NH   16
#define HD   128

typedef __bf16 bf16x8 __attribute__((ext_vector_type(8)));
typedef float f32x4 __attribute__((ext_vector_type(4)));
typedef float f32x16 __attribute__((ext_vector_type(16)));
typedef unsigned short u16x4 __attribute__((ext_vector_type(4)));
typedef unsigned short u16x8 __attribute__((ext_vector_type(8)));
typedef unsigned int u32x4 __attribute__((ext_vector_type(4)));

__device__ __forceinline__ unsigned short f2b(float f) {
  return __builtin_bit_cast(unsigned short, (__bf16)f);
}

__device__ __forceinline__ unsigned cvt_pk_bf16(float lo, float hi) {
  unsigned r;
  asm("v_cvt_pk_bf16_f32 %0, %1, %2" : "=v"(r) : "v"(lo), "v"(hi));
  return r;
}

__device__ __forceinline__ void gl_lds16(const void* g, void* l) {
  __builtin_amdgcn_global_load_lds(
      (const __attribute__((address_space(1))) void*)g,
      (__attribute__((address_space(3))) void*)l, 16, 0, 0);
}

// ---------------- kernel 1: x fp32 -> bf16 ----------------
__global__ void k_cvt_x(const float* __restrict__ x, unsigned short* __restrict__ xb) {
  int i = blockIdx.x * 256 + threadIdx.x;
  const float4* src = (const float4*)x + (size_t)i * 2;
  float4 a = src[0], c = src[1];
  u16x8 o;
  o[0] = f2b(a.x); o[1] = f2b(a.y); o[2] = f2b(a.z); o[3] = f2b(a.w);
  o[4] = f2b(c.x); o[5] = f2b(c.y); o[6] = f2b(c.z); o[7] = f2b(c.w);
  *((u16x8*)xb + i) = o;
}

// ---------------- kernel 2: W fp32 [K][N] -> bf16 Wt [N][K] ----------------
__global__ void k_cvt_w(const float* __restrict__ Wq, const float* __restrict__ Wk,
                        const float* __restrict__ Wv, unsigned short* __restrict__ wts) {
  const float* W = blockIdx.z == 0 ? Wq : (blockIdx.z == 1 ? Wk : Wv);
  unsigned short* out = wts + (size_t)blockIdx.z * DM * DM;
  __shared__ unsigned short t[64 * 68];  // t[col][row]
  int c0 = blockIdx.x * 64, r0 = blockIdx.y * 64;
  int tr = threadIdx.x >> 4, tc = (threadIdx.x & 15) * 4;
#pragma unroll
  for (int p = 0; p < 4; ++p) {
    int r = p * 16 + tr;
    float4 v = *(const float4*)(W + (size_t)(r0 + r) * DM + c0 + tc);
    t[(tc + 0) * 68 + r] = f2b(v.x);
    t[(tc + 1) * 68 + r] = f2b(v.y);
    t[(tc + 2) * 68 + r] = f2b(v.z);
    t[(tc + 3) * 68 + r] = f2b(v.w);
  }
  __syncthreads();
#pragma unroll
  for (int p = 0; p < 4; ++p) {
    int c = p * 16 + tr;
    u16x4 o = *(const u16x4*)&t[c * 68 + tc];
    *(u16x4*)(out + (size_t)(c0 + c) * DM + r0 + tc) = o;
  }
}

// ---------------- kernel 3: z-FUSED QKV GEMM (unchanged from R12) ----------------
#define NTK 64

#define STAGEQ(T)                                                              \
  if ((T) < NTK) {                                                             \
    const int kt_ = (T);                                                       \
    const unsigned ab_ = ((T)&1) * 4096u;                                      \
    const unsigned bb_ = 8192u + ((T)&1) * 24576u;                             \
    gl_lds16(Ag + (size_t)arow * DM + kt_ * 32 + acs * 8,                      \
             &smem[ab_ + wave * 512]);                                         \
    _Pragma("unroll") for (int z_ = 0; z_ < 3; ++z_)                           \
    _Pragma("unroll") for (int p_ = 0; p_ < 2; ++p_)                           \
      gl_lds16(Bg + (size_t)z_ * DM * DM + (size_t)(p_ * 128 + arow) * DM +    \
                   kt_ * 32 + acs * 8,                                         \
               &smem[bb_ + z_ * 8192 + p_ * 4096 + wave * 512]);               \
  }

__global__ __launch_bounds__(512, 2) void k_qkv(
    const unsigned short* __restrict__ xb, const unsigned short* __restrict__ wts,
    unsigned short* __restrict__ qb, unsigned short* __restrict__ kb,
    unsigned short* __restrict__ vtb) {
  __shared__ unsigned short smem[57344];

  const int id = blockIdx.x;
  const int n0 = (id & 7) * 256;
  const int m0 = (id >> 3) * 128;

  const unsigned short* Ag = xb + (size_t)m0 * DM;
  const unsigned short* Bg = wts + (size_t)n0 * DM;

  const int tid = threadIdx.x;
  const int wave = tid >> 6, lane = tid & 63;
  const int lr = lane & 15, lg = lane >> 4;
  const int wr = wave >> 2, wc = wave & 3;
  const int arow = tid >> 2;
  const int acs = (tid & 3) ^ ((arow >> 1) & 3);
  const int rsw = (lr >> 1) & 3;

  f32x4 acc[3][4][4] = {};

  STAGEQ(0);
  asm volatile("s_waitcnt vmcnt(0)" ::: "memory");
  __builtin_amdgcn_s_barrier();

  for (int t = 0; t < NTK; ++t) {
    STAGEQ(t + 1);

    const unsigned ab = (t & 1) * 4096u;
    const unsigned bb = 8192u + (t & 1) * 24576u;

    bf16x8 af[4];
#pragma unroll
    for (int mf = 0; mf < 4; ++mf) {
      int row = wr * 64 + mf * 16 + lr;
      af[mf] = *(const bf16x8*)&smem[ab + row * 32 + ((lg ^ rsw) * 8)];
    }
    __builtin_amdgcn_s_setprio(1);
#pragma unroll
    for (int z = 0; z < 3; ++z)
#pragma unroll
      for (int nf = 0; nf < 4; ++nf) {
        int row = wc * 64 + nf * 16 + lr;
        bf16x8 bq = *(const bf16x8*)&smem[bb + z * 8192 + row * 32 + ((lg ^ rsw) * 8)];
#pragma unroll
        for (int mf = 0; mf < 4; ++mf)
          acc[z][mf][nf] = __builtin_amdgcn_mfma_f32_16x16x32_bf16(
              af[mf], bq, acc[z][mf][nf], 0, 0, 0);
      }
    __builtin_amdgcn_s_setprio(0);

    asm volatile("s_waitcnt lgkmcnt(0)" ::: "memory");
    asm volatile("s_waitcnt vmcnt(0)" ::: "memory");
    __builtin_amdgcn_s_barrier();
  }

#pragma unroll
  for (int z = 0; z < 2; ++z) {
    unsigned short* outp = z == 0 ? qb : kb;
#pragma unroll
    for (int mf = 0; mf < 4; ++mf)
#pragma unroll
      for (int nf = 0; nf < 4; ++nf) {
        int n = n0 + wc * 64 + nf * 16 + lr;
        int h = n >> 7, d = n & 127;
#pragma unroll
        for (int r = 0; r < 4; ++r) {
          int m = m0 + wr * 64 + mf * 16 + lg * 4 + r;
          int b = m >> 11, s = m & 2047;
          outp[(((size_t)(b * NH + h)) * SEQ + s) * HD + d] = f2b(acc[z][mf][nf][r]);
        }
      }
  }
#pragma unroll
  for (int mf = 0; mf < 4; ++mf)
#pragma unroll
    for (int nf = 0; nf < 4; ++nf) {
      int dl = wc * 64 + nf * 16 + lr;
      int gq = wr * 16 + mf * 4 + lg;
      int gs = gq ^ ((dl & 7) << 2);
      u16x4 pk = {f2b(acc[2][mf][nf][0]), f2b(acc[2][mf][nf][1]),
                  f2b(acc[2][mf][nf][2]), f2b(acc[2][mf][nf][3])};
      *(u16x4*)&smem[dl * 128 + gs * 4] = pk;
    }
  asm volatile("s_waitcnt lgkmcnt(0)" ::: "memory");
  __builtin_amdgcn_s_barrier();
  {
    int b = m0 >> 11, sbase = m0 & 2047;
#pragma unroll
    for (int p = 0; p < 8; ++p) {
      int f = p * 512 + tid;
      int dl = f >> 4, c8 = f & 15;
      int g0 = (2 * c8) ^ ((dl & 7) << 2);
      u16x8 v = *(const u16x8*)&smem[dl * 128 + g0 * 4];
      int n = n0 + dl;
      int h = n >> 7, d = n & 127;
      *(u16x8*)(vtb + (((size_t)(b * NH + h)) * HD + d) * SEQ + sbase + c8 * 8) = v;
    }
  }
}

// ---------------- kernel 4: attn, 32x32 in-reg softmax + att[2] pipeline (T15) ----------------
// 512 blocks (heavy-first LPT), 4 waves x 32 q, KVBLK=64. K dbuf + V TRIPLE buffer
// (80KB -> 2 blocks/CU). Per tile: QK(t) MFMA issues, then softmax+pack+PV of t-1
// runs on VALU while MFMA drains. Pack = R12's PROVEN shfl_xor(32)+select (permlane
// rolled back: same-value "+v" asm operands can coalesce to one VGPR -> R13 fail).
__global__ __launch_bounds__(256, 2) void k_attn(
    const unsigned short* __restrict__ qb, const unsigned short* __restrict__ kb,
    const unsigned short* __restrict__ vtb, float* __restrict__ out) {
  __shared__ unsigned short Kl[2][64 * 128];   // [kv][d], chunk-XOR swizzled
  __shared__ unsigned short Vl[3][128 * 64];   // [d][kv], chunk-XOR swizzled, tri-buf

  const int id = blockIdx.x;
  const int x = 15 - (id >> 5);                // heavy subtiles first (LPT)
  const int bh = id & 31;
  const int b = bh >> 4, h = bh & 15;
  const int tid = threadIdx.x;
  const int wave = tid >> 6, lane = tid & 63;
  const int l31 = lane & 31, hi = lane >> 5;

  const unsigned short* Qg = qb + (size_t)bh * SEQ * HD;
  const unsigned short* Kg = kb + (size_t)bh * SEQ * HD;
  const unsigned short* Vg = vtb + (size_t)bh * HD * SEQ;
  const float C = 0.12751744155229827f;  // (1/sqrt(128)) * log2(e)

  const int krow = tid >> 4, kc = tid & 15;
  const int ksw = (kc ^ (krow & 7)) * 8;
  const int vrow = tid >> 3, vc = tid & 7;
  const int vsw = (vc ^ (vrow & 7)) * 8;

#define STG(KV0, KB, VB)                                                       \
  {                                                                            \
    const unsigned short* K_ = Kg + (size_t)(KV0)*HD;                          \
    const unsigned short* V_ = Vg + (KV0);                                     \
    _Pragma("unroll") for (int p = 0; p < 4; ++p) {                            \
      gl_lds16(K_ + (size_t)(p * 16 + krow) * HD + ksw,                        \
               &Kl[KB][(p * 256 + tid) * 8]);                                  \
      gl_lds16(V_ + (size_t)(p * 32 + vrow) * SEQ + vsw,                       \
               &Vl[VB][(p * 256 + tid) * 8]);                                  \
    }                                                                          \
  }

  const int q0 = x * 128;
  const int nt = 2 * x + 2;   // always even
  const int qw = q0 + wave * 32 + l31;

  bf16x8 qf[8];
#pragma unroll
  for (int ks = 0; ks < 8; ++ks)
    qf[ks] = *(const bf16x8*)&Qg[(size_t)qw * HD + ks * 16 + hi * 8];

  f32x16 oacc[4] = {};
  float m_run = -1e30f, l_run = 0.f;
  f32x16 sA0, sA1, sB0, sB1;

#define QK(T, S0, S1)                                                          \
  {                                                                            \
    const int cur_ = (T)&1;                                                    \
    S0 = (f32x16){};                                                           \
    S1 = (f32x16){};                                                           \
    __builtin_amdgcn_s_setprio(1);                                             \
    _Pragma("unroll") for (int ks = 0; ks < 8; ++ks) {                         \
      const int cch = ((2 * ks + hi) ^ (l31 & 7)) * 8;                         \
      bf16x8 k0 = *(const bf16x8*)&Kl[cur_][l31 * 128 + cch];                  \
      bf16x8 k1 = *(const bf16x8*)&Kl[cur_][(32 + l31) * 128 + cch];           \
      S0 = __builtin_amdgcn_mfma_f32_32x32x16_bf16(k0, qf[ks], S0, 0, 0, 0);   \
      S1 = __builtin_amdgcn_mfma_f32_32x32x16_bf16(k1, qf[ks], S1, 0, 0, 0);   \
    }                                                                          \
    __builtin_amdgcn_s_setprio(0);                                             \
  }

#define SMPV(P, S0, S1)                                                        \
  {                                                                            \
    if ((P) >= nt - 2) {                                                       \
      const int kv0_ = (P)*64;                                                 \
      _Pragma("unroll") for (int r = 0; r < 16; ++r) {                         \
        const int crow = (r & 3) + 8 * (r >> 2) + 4 * hi;                      \
        if (kv0_ + crow > qw) S0[r] = -1e30f;                                  \
        if (kv0_ + 32 + crow > qw) S1[r] = -1e30f;                             \
      }                                                                        \
    }                                                                          \
    float vm = -1e30f;                                                         \
    _Pragma("unroll") for (int r = 0; r < 16; ++r)                             \
        vm = fmaxf(vm, fmaxf(S0[r], S1[r]));                                   \
    vm = fmaxf(vm, __shfl_xor(vm, 32));                                        \
    if (__any(vm - m_run > 60.0f)) {                                           \
      const float nm = fmaxf(m_run, vm);                                       \
      const float pfac = exp2f((m_run - nm) * C);                              \
      _Pragma("unroll") for (int r = 0; r < 16; ++r) {                         \
        const int crow = (r & 3) + 8 * (r >> 2) + 4 * hi;                      \
        const float f = __shfl(pfac, crow);                                    \
        _Pragma("unroll") for (int db = 0; db < 4; ++db) oacc[db][r] *= f;     \
      }                                                                        \
      l_run *= pfac;                                                           \
      m_run = nm;                                                              \
    }                                                                          \
    const float mC = m_run * C;                                                \
    float ss = 0.f;                                                            \
    _Pragma("unroll") for (int r = 0; r < 16; ++r) {                           \
      S0[r] = exp2f(S0[r] * C - mC);                                           \
      ss += S0[r];                                                             \
      S1[r] = exp2f(S1[r] * C - mC);                                           \
      ss += S1[r];                                                             \
    }                                                                          \
    ss += __shfl_xor(ss, 32);                                                  \
    l_run += ss;                                                               \
    unsigned u[16], xw[16];                                                    \
    _Pragma("unroll") for (int i = 0; i < 8; ++i) {                            \
      u[i] = cvt_pk_bf16(S0[2 * i], S0[2 * i + 1]);                            \
      u[8 + i] = cvt_pk_bf16(S1[2 * i], S1[2 * i + 1]);                        \
    }                                                                          \
    _Pragma("unroll") for (int i = 0; i < 16; ++i)                             \
        xw[i] = (unsigned)__shfl_xor((int)u[i], 32);                           \
    bf16x8 pf[4];                                                              \
    _Pragma("unroll") for (int kb2 = 0; kb2 < 2; ++kb2) {                      \
      const int o = kb2 * 8;                                                   \
      u32x4 w0, w1;                                                            \
      w0[0] = hi ? xw[o + 2] : u[o + 0];                                       \
      w0[1] = hi ? xw[o + 3] : u[o + 1];                                       \
      w0[2] = hi ? u[o + 2] : xw[o + 0];                                       \
      w0[3] = hi ? u[o + 3] : xw[o + 1];                                       \
      w1[0] = hi ? xw[o + 6] : u[o + 4];                                       \
      w1[1] = hi ? xw[o + 7] : u[o + 5];                                       \
      w1[2] = hi ? u[o + 6] : xw[o + 4];                                       \
      w1[3] = hi ? u[o + 7] : xw[o + 5];                                       \
      pf[kb2 * 2 + 0] = __builtin_bit_cast(bf16x8, w0);                        \
      pf[kb2 * 2 + 1] = __builtin_bit_cast(bf16x8, w1);                        \
    }                                                                          \
    const int vb_ = (P) % 3;                                                   \
    __builtin_amdgcn_s_setprio(1);                                             \
    _Pragma("unroll") for (int db = 0; db < 4; ++db)                           \
    _Pragma("unroll") for (int sl = 0; sl < 4; ++sl) {                         \
      bf16x8 vf = *(const bf16x8*)&Vl[vb_][(db * 32 + l31) * 64 +              \
                                          (((2 * sl + hi) ^ (l31 & 7)) * 8)];  \
      oacc[db] =                                                               \
          __builtin_amdgcn_mfma_f32_32x32x16_bf16(pf[sl], vf, oacc[db], 0, 0, 0);\
    }                                                                          \
    __builtin_amdgcn_s_setprio(0);                                             \
  }

  // prologue: stage tiles 0,1; compute QK(0)
  STG(0, 0, 0);
  STG(64, 1, 1);
  asm volatile("s_waitcnt vmcnt(8)" ::: "memory");  // tile 0 landed
  __builtin_amdgcn_s_barrier();
  QK(0, sA0, sA1);
  __builtin_amdgcn_s_barrier();

  int t = 1;
  while (t < nt) {
    // tile t (odd): QK -> sB, finish tile t-1 from sA
    if (t + 1 < nt) {
      STG((t + 1) * 64, (t + 1) & 1, (t + 1) % 3);
      asm volatile("s_waitcnt vmcnt(8)" ::: "memory");
    } else {
      asm volatile("s_waitcnt vmcnt(0)" ::: "memory");
    }
    __builtin_amdgcn_s_barrier();
    QK(t, sB0, sB1);
    SMPV(t - 1, sA0, sA1);
    __builtin_amdgcn_s_barrier();
    ++t;
    if (t >= nt) break;
    // tile t (even): QK -> sA, finish tile t-1 from sB
    if (t + 1 < nt) {
      STG((t + 1) * 64, (t + 1) & 1, (t + 1) % 3);
      asm volatile("s_waitcnt vmcnt(8)" ::: "memory");
    } else {
      asm volatile("s_waitcnt vmcnt(0)" ::: "memory");
    }
    __builtin_amdgcn_s_barrier();
    QK(t, sA0, sA1);
    SMPV(t - 1, sB0, sB1);
    __builtin_amdgcn_s_barrier();
    ++t;
  }
  // epilogue: last tile nt-1 (odd index) lives in sB
  SMPV(nt - 1, sB0, sB1);

  // ---- normalize + store fp32 ----
#pragma unroll
  for (int r = 0; r < 16; ++r) {
    const int crow = (r & 3) + 8 * (r >> 2) + 4 * hi;
    const float li = 1.0f / __shfl(l_run, crow);
    const int q = q0 + wave * 32 + crow;
    float* orow = out + ((size_t)b * SEQ + q) * DM + h * HD;
#pragma unroll
    for (int db = 0; db < 4; ++db)
      orow[db * 32 + l31] = oacc[db][r] * li;
  }
}

// ---------------- launcher ----------------
extern "C" void kernel_launch(void* const* d_in, const int* in_sizes, int n_in,
                              void* d_out, int out_size, void* d_ws, size_t ws_size,
                              hipStream_t stream) {
  const float* x  = (const float*)d_in[0];
  const float* Wq = (const float*)d_in[1];
  const float* Wk = (const float*)d_in[2];
  const float* Wv = (const float*)d_in[3];
  float* out = (float*)d_out;
  char* ws = (char*)d_ws;

  unsigned short* xb  = (unsigned short*)(ws);              // 4096x2048 bf16   (16 MB)
  unsigned short* wt  = (unsigned short*)(ws + 16777216);   // 3x 2048x2048 bf16 (24 MB)
  unsigned short* qb  = (unsigned short*)(ws + 41943040);   // [32][2048][128]  (16 MB)
  unsigned short* kb  = (unsigned short*)(ws + 58720256);   // [32][2048][128]  (16 MB)
  unsigned short* vtb = (unsigned short*)(ws + 75497472);   // [32][128][2048]  (16 MB)

  k_cvt_x<<<4096, 256, 0, stream>>>(x, xb);
  dim3 gw(32, 32, 3);
  k_cvt_w<<<gw, 256, 0, stream>>>(Wq, Wk, Wv, wt);
  k_qkv<<<256, 512, 0, stream>>>(xb, wt, qb, kb, vtb);
  k_attn<<<512, 256, 0, stream>>>(qb, kb, vtb, out);
}

// Round 15
// 200.033 us; speedup vs baseline: 1.4173x; 1.4173x over previous
//
#include <hip/hip_runtime.h>

#define DM   2048
#define SEQ  2048
#define NB   2
#define NH   16
#define HD   128

typedef __bf16 bf16x8 __attribute__((ext_vector_type(8)));
typedef float f32x4 __attribute__((ext_vector_type(4)));
typedef float f32x16 __attribute__((ext_vector_type(16)));
typedef unsigned short u16x4 __attribute__((ext_vector_type(4)));
typedef unsigned short u16x8 __attribute__((ext_vector_type(8)));
typedef unsigned int u32x4 __attribute__((ext_vector_type(4)));

__device__ __forceinline__ unsigned short f2b(float f) {
  return __builtin_bit_cast(unsigned short, (__bf16)f);
}

__device__ __forceinline__ unsigned cvt_pk_bf16(float lo, float hi) {
  unsigned r;
  asm("v_cvt_pk_bf16_f32 %0, %1, %2" : "=v"(r) : "v"(lo), "v"(hi));
  return r;
}

__device__ __forceinline__ void gl_lds16(const void* g, void* l) {
  __builtin_amdgcn_global_load_lds(
      (const __attribute__((address_space(1))) void*)g,
      (__attribute__((address_space(3))) void*)l, 16, 0, 0);
}

// ---------------- kernel 1: x fp32 -> bf16 ----------------
__global__ void k_cvt_x(const float* __restrict__ x, unsigned short* __restrict__ xb) {
  int i = blockIdx.x * 256 + threadIdx.x;
  const float4* src = (const float4*)x + (size_t)i * 2;
  float4 a = src[0], c = src[1];
  u16x8 o;
  o[0] = f2b(a.x); o[1] = f2b(a.y); o[2] = f2b(a.z); o[3] = f2b(a.w);
  o[4] = f2b(c.x); o[5] = f2b(c.y); o[6] = f2b(c.z); o[7] = f2b(c.w);
  *((u16x8*)xb + i) = o;
}

// ---------------- kernel 2: W fp32 [K][N] -> bf16 Wt [N][K] ----------------
__global__ void k_cvt_w(const float* __restrict__ Wq, const float* __restrict__ Wk,
                        const float* __restrict__ Wv, unsigned short* __restrict__ wts) {
  const float* W = blockIdx.z == 0 ? Wq : (blockIdx.z == 1 ? Wk : Wv);
  unsigned short* out = wts + (size_t)blockIdx.z * DM * DM;
  __shared__ unsigned short t[64 * 68];  // t[col][row]
  int c0 = blockIdx.x * 64, r0 = blockIdx.y * 64;
  int tr = threadIdx.x >> 4, tc = (threadIdx.x & 15) * 4;
#pragma unroll
  for (int p = 0; p < 4; ++p) {
    int r = p * 16 + tr;
    float4 v = *(const float4*)(W + (size_t)(r0 + r) * DM + c0 + tc);
    t[(tc + 0) * 68 + r] = f2b(v.x);
    t[(tc + 1) * 68 + r] = f2b(v.y);
    t[(tc + 2) * 68 + r] = f2b(v.z);
    t[(tc + 3) * 68 + r] = f2b(v.w);
  }
  __syncthreads();
#pragma unroll
  for (int p = 0; p < 4; ++p) {
    int c = p * 16 + tr;
    u16x4 o = *(const u16x4*)&t[c * 68 + tc];
    *(u16x4*)(out + (size_t)(c0 + c) * DM + r0 + tc) = o;
  }
}

// ---------------- kernel 3: z-FUSED QKV GEMM (R12-exact) ----------------
#define NTK 64

#define STAGEQ(T)                                                              \
  if ((T) < NTK) {                                                             \
    const int kt_ = (T);                                                       \
    const unsigned ab_ = ((T)&1) * 4096u;                                      \
    const unsigned bb_ = 8192u + ((T)&1) * 24576u;                             \
    gl_lds16(Ag + (size_t)arow * DM + kt_ * 32 + acs * 8,                      \
             &smem[ab_ + wave * 512]);                                         \
    _Pragma("unroll") for (int z_ = 0; z_ < 3; ++z_)                           \
    _Pragma("unroll") for (int p_ = 0; p_ < 2; ++p_)                           \
      gl_lds16(Bg + (size_t)z_ * DM * DM + (size_t)(p_ * 128 + arow) * DM +    \
                   kt_ * 32 + acs * 8,                                         \
               &smem[bb_ + z_ * 8192 + p_ * 4096 + wave * 512]);               \
  }

__global__ __launch_bounds__(512, 2) void k_qkv(
    const unsigned short* __restrict__ xb, const unsigned short* __restrict__ wts,
    unsigned short* __restrict__ qb, unsigned short* __restrict__ kb,
    unsigned short* __restrict__ vtb) {
  __shared__ unsigned short smem[57344];

  const int id = blockIdx.x;
  const int n0 = (id & 7) * 256;
  const int m0 = (id >> 3) * 128;

  const unsigned short* Ag = xb + (size_t)m0 * DM;
  const unsigned short* Bg = wts + (size_t)n0 * DM;

  const int tid = threadIdx.x;
  const int wave = tid >> 6, lane = tid & 63;
  const int lr = lane & 15, lg = lane >> 4;
  const int wr = wave >> 2, wc = wave & 3;
  const int arow = tid >> 2;
  const int acs = (tid & 3) ^ ((arow >> 1) & 3);
  const int rsw = (lr >> 1) & 3;

  f32x4 acc[3][4][4] = {};

  STAGEQ(0);
  asm volatile("s_waitcnt vmcnt(0)" ::: "memory");
  __builtin_amdgcn_s_barrier();

  for (int t = 0; t < NTK; ++t) {
    STAGEQ(t + 1);

    const unsigned ab = (t & 1) * 4096u;
    const unsigned bb = 8192u + (t & 1) * 24576u;

    bf16x8 af[4];
#pragma unroll
    for (int mf = 0; mf < 4; ++mf) {
      int row = wr * 64 + mf * 16 + lr;
      af[mf] = *(const bf16x8*)&smem[ab + row * 32 + ((lg ^ rsw) * 8)];
    }
    __builtin_amdgcn_s_setprio(1);
#pragma unroll
    for (int z = 0; z < 3; ++z)
#pragma unroll
      for (int nf = 0; nf < 4; ++nf) {
        int row = wc * 64 + nf * 16 + lr;
        bf16x8 bq = *(const bf16x8*)&smem[bb + z * 8192 + row * 32 + ((lg ^ rsw) * 8)];
#pragma unroll
        for (int mf = 0; mf < 4; ++mf)
          acc[z][mf][nf] = __builtin_amdgcn_mfma_f32_16x16x32_bf16(
              af[mf], bq, acc[z][mf][nf], 0, 0, 0);
      }
    __builtin_amdgcn_s_setprio(0);

    asm volatile("s_waitcnt lgkmcnt(0)" ::: "memory");
    asm volatile("s_waitcnt vmcnt(0)" ::: "memory");
    __builtin_amdgcn_s_barrier();
  }

#pragma unroll
  for (int z = 0; z < 2; ++z) {
    unsigned short* outp = z == 0 ? qb : kb;
#pragma unroll
    for (int mf = 0; mf < 4; ++mf)
#pragma unroll
      for (int nf = 0; nf < 4; ++nf) {
        int n = n0 + wc * 64 + nf * 16 + lr;
        int h = n >> 7, d = n & 127;
#pragma unroll
        for (int r = 0; r < 4; ++r) {
          int m = m0 + wr * 64 + mf * 16 + lg * 4 + r;
          int b = m >> 11, s = m & 2047;
          outp[(((size_t)(b * NH + h)) * SEQ + s) * HD + d] = f2b(acc[z][mf][nf][r]);
        }
      }
  }
#pragma unroll
  for (int mf = 0; mf < 4; ++mf)
#pragma unroll
    for (int nf = 0; nf < 4; ++nf) {
      int dl = wc * 64 + nf * 16 + lr;
      int gq = wr * 16 + mf * 4 + lg;
      int gs = gq ^ ((dl & 7) << 2);
      u16x4 pk = {f2b(acc[2][mf][nf][0]), f2b(acc[2][mf][nf][1]),
                  f2b(acc[2][mf][nf][2]), f2b(acc[2][mf][nf][3])};
      *(u16x4*)&smem[dl * 128 + gs * 4] = pk;
    }
  asm volatile("s_waitcnt lgkmcnt(0)" ::: "memory");
  __builtin_amdgcn_s_barrier();
  {
    int b = m0 >> 11, sbase = m0 & 2047;
#pragma unroll
    for (int p = 0; p < 8; ++p) {
      int f = p * 512 + tid;
      int dl = f >> 4, c8 = f & 15;
      int g0 = (2 * c8) ^ ((dl & 7) << 2);
      u16x8 v = *(const u16x8*)&smem[dl * 128 + g0 * 4];
      int n = n0 + dl;
      int h = n >> 7, d = n & 127;
      *(u16x8*)(vtb + (((size_t)(b * NH + h)) * HD + d) * SEQ + sbase + c8 * 8) = v;
    }
  }
}

// ---------------- kernel 4: attn (R12-exact structure; pack shuffles halved) ----------------
// 512 blocks, 4 waves x 32 q, KVBLK=64, K/V dbuf 64KB -> 2 blocks/CU.
// Pack: pre-select per half so ONE shfl_xor(32) serves both halves' cross needs
// (16 -> 8 ds_bpermute per tile; +8 cndmask). Truth-table-verified vs R12 pack.
__global__ __launch_bounds__(256, 2) void k_attn(
    const unsigned short* __restrict__ qb, const unsigned short* __restrict__ kb,
    const unsigned short* __restrict__ vtb, float* __restrict__ out) {
  __shared__ unsigned short Kl[2][64 * 128];   // [kv][d], chunk-XOR swizzled
  __shared__ unsigned short Vl[2][128 * 64];   // [d][kv], chunk-XOR swizzled

  const int id = blockIdx.x;
  const int x = 15 - (id >> 5);                // heavy subtiles first
  const int bh = id & 31;
  const int b = bh >> 4, h = bh & 15;
  const int tid = threadIdx.x;
  const int wave = tid >> 6, lane = tid & 63;
  const int l31 = lane & 31, hi = lane >> 5;

  const unsigned short* Qg = qb + (size_t)bh * SEQ * HD;
  const unsigned short* Kg = kb + (size_t)bh * SEQ * HD;
  const unsigned short* Vg = vtb + (size_t)bh * HD * SEQ;
  const float C = 0.12751744155229827f;  // (1/sqrt(128)) * log2(e)

  const int krow = tid >> 4, kc = tid & 15;
  const int ksw = (kc ^ (krow & 7)) * 8;
  const int vrow = tid >> 3, vc = tid & 7;
  const int vsw = (vc ^ (vrow & 7)) * 8;

#define STAGE_T(KV0, BUF)                                                      \
  {                                                                            \
    const unsigned short* K_ = Kg + (size_t)(KV0)*HD;                          \
    const unsigned short* V_ = Vg + (KV0);                                     \
    _Pragma("unroll") for (int p = 0; p < 4; ++p) {                            \
      gl_lds16(K_ + (size_t)(p * 16 + krow) * HD + ksw,                        \
               &Kl[BUF][(p * 256 + tid) * 8]);                                 \
      gl_lds16(V_ + (size_t)(p * 32 + vrow) * SEQ + vsw,                       \
               &Vl[BUF][(p * 256 + tid) * 8]);                                 \
    }                                                                          \
  }

  const int q0 = x * 128;
  const int nt = 2 * x + 2;
  const int qw = q0 + wave * 32 + l31;   // this lane's q-row

  bf16x8 qf[8];
#pragma unroll
  for (int ks = 0; ks < 8; ++ks)
    qf[ks] = *(const bf16x8*)&Qg[(size_t)qw * HD + ks * 16 + hi * 8];

  f32x16 oacc[4] = {};   // [dblk]; lane: col d = dblk*32+l31, row q = crow(r,hi)
  float m_run = -1e30f, l_run = 0.f;

  STAGE_T(0, 0);

  for (int t = 0; t < nt; ++t) {
    const int cur = t & 1;
    if (t + 1 < nt) {
      STAGE_T((t + 1) * 64, cur ^ 1);
      asm volatile("s_waitcnt vmcnt(8)" ::: "memory");
    } else {
      asm volatile("s_waitcnt vmcnt(0)" ::: "memory");
    }
    __builtin_amdgcn_s_barrier();

    // ---- S^T = K . Q^T : s0 = kv rows [0,32), s1 = [32,64); col q = l31 ----
    f32x16 s0 = {}, s1 = {};
    __builtin_amdgcn_s_setprio(1);
#pragma unroll
    for (int ks = 0; ks < 8; ++ks) {
      const int cch = ((2 * ks + hi) ^ (l31 & 7)) * 8;
      bf16x8 k0 = *(const bf16x8*)&Kl[cur][l31 * 128 + cch];
      bf16x8 k1 = *(const bf16x8*)&Kl[cur][(32 + l31) * 128 + cch];
      s0 = __builtin_amdgcn_mfma_f32_32x32x16_bf16(k0, qf[ks], s0, 0, 0, 0);
      s1 = __builtin_amdgcn_mfma_f32_32x32x16_bf16(k1, qf[ks], s1, 0, 0, 0);
    }
    __builtin_amdgcn_s_setprio(0);

    if (t >= nt - 2) {  // diagonal tiles: causal mask
      const int kv0 = t * 64;
#pragma unroll
      for (int r = 0; r < 16; ++r) {
        const int crow = (r & 3) + 8 * (r >> 2) + 4 * hi;
        if (kv0 + crow > qw) s0[r] = -1e30f;
        if (kv0 + 32 + crow > qw) s1[r] = -1e30f;
      }
    }

    // ---- in-lane row max + one cross-half combine ----
    float vm = -1e30f;
#pragma unroll
    for (int r = 0; r < 16; ++r) vm = fmaxf(vm, fmaxf(s0[r], s1[r]));
    vm = fmaxf(vm, __shfl_xor(vm, 32));

    // ---- defer-max (T13) ----
    if (__any(vm - m_run > 60.0f)) {
      const float nm = fmaxf(m_run, vm);
      const float pfac = exp2f((m_run - nm) * C);
#pragma unroll
      for (int r = 0; r < 16; ++r) {
        const int crow = (r & 3) + 8 * (r >> 2) + 4 * hi;
        const float f = __shfl(pfac, crow);
#pragma unroll
        for (int db = 0; db < 4; ++db) oacc[db][r] *= f;
      }
      l_run *= pfac;
      m_run = nm;
    }
    const float mC = m_run * C;

    // ---- exp + in-lane sum + one combine ----
    float ss = 0.f;
#pragma unroll
    for (int r = 0; r < 16; ++r) {
      s0[r] = exp2f(s0[r] * C - mC); ss += s0[r];
      s1[r] = exp2f(s1[r] * C - mC); ss += s1[r];
    }
    ss += __shfl_xor(ss, 32);
    l_run += ss;

    // ---- pack P (cvt_pk) + half-exchange -> PV A-frags (8 shfls, was 16) ----
    unsigned u[16];
#pragma unroll
    for (int i = 0; i < 8; ++i) {
      u[i] = cvt_pk_bf16(s0[2 * i], s0[2 * i + 1]);
      u[8 + i] = cvt_pk_bf16(s1[2 * i], s1[2 * i + 1]);
    }

    bf16x8 pf[4];
#pragma unroll
    for (int kb2 = 0; kb2 < 2; ++kb2) {
      const int o = kb2 * 8;
      // one shuffle serves both halves: lo needs partner u[o+0..1]/u[o+4..5],
      // hi needs partner u[o+2..3]/u[o+6..7] -> pre-select then shfl_xor(32).
      unsigned a1 = hi ? u[o + 0] : u[o + 2];
      unsigned a2 = hi ? u[o + 1] : u[o + 3];
      unsigned a3 = hi ? u[o + 4] : u[o + 6];
      unsigned a4 = hi ? u[o + 5] : u[o + 7];
      unsigned t1 = (unsigned)__shfl_xor((int)a1, 32);
      unsigned t2 = (unsigned)__shfl_xor((int)a2, 32);
      unsigned t3 = (unsigned)__shfl_xor((int)a3, 32);
      unsigned t4 = (unsigned)__shfl_xor((int)a4, 32);
      u32x4 w0, w1;
      w0[0] = hi ? t1 : u[o + 0];
      w0[1] = hi ? t2 : u[o + 1];
      w0[2] = hi ? u[o + 2] : t1;
      w0[3] = hi ? u[o + 3] : t2;
      w1[0] = hi ? t3 : u[o + 4];
      w1[1] = hi ? t4 : u[o + 5];
      w1[2] = hi ? u[o + 6] : t3;
      w1[3] = hi ? u[o + 7] : t4;
      pf[kb2 * 2 + 0] = __builtin_bit_cast(bf16x8, w0);
      pf[kb2 * 2 + 1] = __builtin_bit_cast(bf16x8, w1);
    }

    // ---- O += P . V ----
    __builtin_amdgcn_s_setprio(1);
#pragma unroll
    for (int db = 0; db < 4; ++db) {
#pragma unroll
      for (int sl = 0; sl < 4; ++sl) {
        bf16x8 vf = *(const bf16x8*)&Vl[cur][(db * 32 + l31) * 64 +
                                            (((2 * sl + hi) ^ (l31 & 7)) * 8)];
        oacc[db] = __builtin_amdgcn_mfma_f32_32x32x16_bf16(pf[sl], vf, oacc[db], 0, 0, 0);
      }
    }
    __builtin_amdgcn_s_setprio(0);
    __builtin_amdgcn_s_barrier();
  }

  // ---- normalize + store fp32 ----
#pragma unroll
  for (int r = 0; r < 16; ++r) {
    const int crow = (r & 3) + 8 * (r >> 2) + 4 * hi;
    const float li = 1.0f / __shfl(l_run, crow);
    const int q = q0 + wave * 32 + crow;
    float* orow = out + ((size_t)b * SEQ + q) * DM + h * HD;
#pragma unroll
    for (int db = 0; db < 4; ++db)
      orow[db * 32 + l31] = oacc[db][r] * li;
  }
}

// ---------------- launcher ----------------
extern "C" void kernel_launch(void* const* d_in, const int* in_sizes, int n_in,
                              void* d_out, int out_size, void* d_ws, size_t ws_size,
                              hipStream_t stream) {
  const float* x  = (const float*)d_in[0];
  const float* Wq = (const float*)d_in[1];
  const float* Wk = (const float*)d_in[2];
  const float* Wv = (const float*)d_in[3];
  float* out = (float*)d_out;
  char* ws = (char*)d_ws;

  unsigned short* xb  = (unsigned short*)(ws);              // 4096x2048 bf16   (16 MB)
  unsigned short* wt  = (unsigned short*)(ws + 16777216);   // 3x 2048x2048 bf16 (24 MB)
  unsigned short* qb  = (unsigned short*)(ws + 41943040);   // [32][2048][128]  (16 MB)
  unsigned short* kb  = (unsigned short*)(ws + 58720256);   // [32][2048][128]  (16 MB)
  unsigned short* vtb = (unsigned short*)(ws + 75497472);   // [32][128][2048]  (16 MB)

  k_cvt_x<<<4096, 256, 0, stream>>>(x, xb);
  dim3 gw(32, 32, 3);
  k_cvt_w<<<gw, 256, 0, stream>>>(Wq, Wk, Wv, wt);
  k_qkv<<<256, 512, 0, stream>>>(xb, wt, qb, kb, vtb);
  k_attn<<<512, 256, 0, stream>>>(qb, kb, vtb, out);
}

// Round 16
// 198.817 us; speedup vs baseline: 1.4260x; 1.0061x over previous
//
#include <hip/hip_runtime.h>

#define DM   2048
#define SEQ  2048
#define NB   2
#define NH   16
#define HD   128

typedef __bf16 bf16x8 __attribute__((ext_vector_type(8)));
typedef float f32x4 __attribute__((ext_vector_type(4)));
typedef float f32x16 __attribute__((ext_vector_type(16)));
typedef unsigned short u16x4 __attribute__((ext_vector_type(4)));
typedef unsigned short u16x8 __attribute__((ext_vector_type(8)));
typedef unsigned int u32x4 __attribute__((ext_vector_type(4)));

__device__ __forceinline__ unsigned short f2b(float f) {
  return __builtin_bit_cast(unsigned short, (__bf16)f);
}

__device__ __forceinline__ unsigned cvt_pk_bf16(float lo, float hi) {
  unsigned r;
  asm("v_cvt_pk_bf16_f32 %0, %1, %2" : "=v"(r) : "v"(lo), "v"(hi));
  return r;
}

__device__ __forceinline__ void gl_lds16(const void* g, void* l) {
  __builtin_amdgcn_global_load_lds(
      (const __attribute__((address_space(1))) void*)g,
      (__attribute__((address_space(3))) void*)l, 16, 0, 0);
}

// ---------------- kernel 1: x fp32 -> bf16 ----------------
__global__ void k_cvt_x(const float* __restrict__ x, unsigned short* __restrict__ xb) {
  int i = blockIdx.x * 256 + threadIdx.x;
  const float4* src = (const float4*)x + (size_t)i * 2;
  float4 a = src[0], c = src[1];
  u16x8 o;
  o[0] = f2b(a.x); o[1] = f2b(a.y); o[2] = f2b(a.z); o[3] = f2b(a.w);
  o[4] = f2b(c.x); o[5] = f2b(c.y); o[6] = f2b(c.z); o[7] = f2b(c.w);
  *((u16x8*)xb + i) = o;
}

// ---------------- kernel 2: W fp32 [K][N] -> bf16 Wt [N][K] ----------------
__global__ void k_cvt_w(const float* __restrict__ Wq, const float* __restrict__ Wk,
                        const float* __restrict__ Wv, unsigned short* __restrict__ wts) {
  const float* W = blockIdx.z == 0 ? Wq : (blockIdx.z == 1 ? Wk : Wv);
  unsigned short* out = wts + (size_t)blockIdx.z * DM * DM;
  __shared__ unsigned short t[64 * 68];  // t[col][row]
  int c0 = blockIdx.x * 64, r0 = blockIdx.y * 64;
  int tr = threadIdx.x >> 4, tc = (threadIdx.x & 15) * 4;
#pragma unroll
  for (int p = 0; p < 4; ++p) {
    int r = p * 16 + tr;
    float4 v = *(const float4*)(W + (size_t)(r0 + r) * DM + c0 + tc);
    t[(tc + 0) * 68 + r] = f2b(v.x);
    t[(tc + 1) * 68 + r] = f2b(v.y);
    t[(tc + 2) * 68 + r] = f2b(v.z);
    t[(tc + 3) * 68 + r] = f2b(v.w);
  }
  __syncthreads();
#pragma unroll
  for (int p = 0; p < 4; ++p) {
    int c = p * 16 + tr;
    u16x4 o = *(const u16x4*)&t[c * 68 + tc];
    *(u16x4*)(out + (size_t)(c0 + c) * DM + r0 + tc) = o;
  }
}

// ---------------- kernel 3: z-FUSED QKV GEMM (R12-exact) ----------------
#define NTK 64

#define STAGEQ(T)                                                              \
  if ((T) < NTK) {                                                             \
    const int kt_ = (T);                                                       \
    const unsigned ab_ = ((T)&1) * 4096u;                                      \
    const unsigned bb_ = 8192u + ((T)&1) * 24576u;                             \
    gl_lds16(Ag + (size_t)arow * DM + kt_ * 32 + acs * 8,                      \
             &smem[ab_ + wave * 512]);                                         \
    _Pragma("unroll") for (int z_ = 0; z_ < 3; ++z_)                           \
    _Pragma("unroll") for (int p_ = 0; p_ < 2; ++p_)                           \
      gl_lds16(Bg + (size_t)z_ * DM * DM + (size_t)(p_ * 128 + arow) * DM +    \
                   kt_ * 32 + acs * 8,                                         \
               &smem[bb_ + z_ * 8192 + p_ * 4096 + wave * 512]);               \
  }

__global__ __launch_bounds__(512, 2) void k_qkv(
    const unsigned short* __restrict__ xb, const unsigned short* __restrict__ wts,
    unsigned short* __restrict__ qb, unsigned short* __restrict__ kb,
    unsigned short* __restrict__ vtb) {
  __shared__ unsigned short smem[57344];

  const int id = blockIdx.x;
  const int n0 = (id & 7) * 256;
  const int m0 = (id >> 3) * 128;

  const unsigned short* Ag = xb + (size_t)m0 * DM;
  const unsigned short* Bg = wts + (size_t)n0 * DM;

  const int tid = threadIdx.x;
  const int wave = tid >> 6, lane = tid & 63;
  const int lr = lane & 15, lg = lane >> 4;
  const int wr = wave >> 2, wc = wave & 3;
  const int arow = tid >> 2;
  const int acs = (tid & 3) ^ ((arow >> 1) & 3);
  const int rsw = (lr >> 1) & 3;

  f32x4 acc[3][4][4] = {};

  STAGEQ(0);
  asm volatile("s_waitcnt vmcnt(0)" ::: "memory");
  __builtin_amdgcn_s_barrier();

  for (int t = 0; t < NTK; ++t) {
    STAGEQ(t + 1);

    const unsigned ab = (t & 1) * 4096u;
    const unsigned bb = 8192u + (t & 1) * 24576u;

    bf16x8 af[4];
#pragma unroll
    for (int mf = 0; mf < 4; ++mf) {
      int row = wr * 64 + mf * 16 + lr;
      af[mf] = *(const bf16x8*)&smem[ab + row * 32 + ((lg ^ rsw) * 8)];
    }
    __builtin_amdgcn_s_setprio(1);
#pragma unroll
    for (int z = 0; z < 3; ++z)
#pragma unroll
      for (int nf = 0; nf < 4; ++nf) {
        int row = wc * 64 + nf * 16 + lr;
        bf16x8 bq = *(const bf16x8*)&smem[bb + z * 8192 + row * 32 + ((lg ^ rsw) * 8)];
#pragma unroll
        for (int mf = 0; mf < 4; ++mf)
          acc[z][mf][nf] = __builtin_amdgcn_mfma_f32_16x16x32_bf16(
              af[mf], bq, acc[z][mf][nf], 0, 0, 0);
      }
    __builtin_amdgcn_s_setprio(0);

    asm volatile("s_waitcnt lgkmcnt(0)" ::: "memory");
    asm volatile("s_waitcnt vmcnt(0)" ::: "memory");
    __builtin_amdgcn_s_barrier();
  }

#pragma unroll
  for (int z = 0; z < 2; ++z) {
    unsigned short* outp = z == 0 ? qb : kb;
#pragma unroll
    for (int mf = 0; mf < 4; ++mf)
#pragma unroll
      for (int nf = 0; nf < 4; ++nf) {
        int n = n0 + wc * 64 + nf * 16 + lr;
        int h = n >> 7, d = n & 127;
#pragma unroll
        for (int r = 0; r < 4; ++r) {
          int m = m0 + wr * 64 + mf * 16 + lg * 4 + r;
          int b = m >> 11, s = m & 2047;
          outp[(((size_t)(b * NH + h)) * SEQ + s) * HD + d] = f2b(acc[z][mf][nf][r]);
        }
      }
  }
#pragma unroll
  for (int mf = 0; mf < 4; ++mf)
#pragma unroll
    for (int nf = 0; nf < 4; ++nf) {
      int dl = wc * 64 + nf * 16 + lr;
      int gq = wr * 16 + mf * 4 + lg;
      int gs = gq ^ ((dl & 7) << 2);
      u16x4 pk = {f2b(acc[2][mf][nf][0]), f2b(acc[2][mf][nf][1]),
                  f2b(acc[2][mf][nf][2]), f2b(acc[2][mf][nf][3])};
      *(u16x4*)&smem[dl * 128 + gs * 4] = pk;
    }
  asm volatile("s_waitcnt lgkmcnt(0)" ::: "memory");
  __builtin_amdgcn_s_barrier();
  {
    int b = m0 >> 11, sbase = m0 & 2047;
#pragma unroll
    for (int p = 0; p < 8; ++p) {
      int f = p * 512 + tid;
      int dl = f >> 4, c8 = f & 15;
      int g0 = (2 * c8) ^ ((dl & 7) << 2);
      u16x8 v = *(const u16x8*)&smem[dl * 128 + g0 * 4];
      int n = n0 + dl;
      int h = n >> 7, d = n & 127;
      *(u16x8*)(vtb + (((size_t)(b * NH + h)) * HD + d) * SEQ + sbase + c8 * 8) = v;
    }
  }
}

// ---------------- kernel 4: attn (R15-exact; CU-complementary pairing remap) ----------------
// 512 blocks, 2/CU co-resident. Breadth-first dispatch puts ids {c, c+256} on CU c:
// id<256 -> x=15-(id>>5) (heavy), id>=256 -> x=(id-256)>>5 (light) => per-CU pair
// (15-a, a) = uniform 34 tiles on every CU; pair shares bh (same K/V in L2).
__global__ __launch_bounds__(256, 2) void k_attn(
    const unsigned short* __restrict__ qb, const unsigned short* __restrict__ kb,
    const unsigned short* __restrict__ vtb, float* __restrict__ out) {
  __shared__ unsigned short Kl[2][64 * 128];   // [kv][d], chunk-XOR swizzled
  __shared__ unsigned short Vl[2][128 * 64];   // [d][kv], chunk-XOR swizzled

  const int id = blockIdx.x;
  const int a = (id & 255) >> 5;               // 0..7
  const int x = (id < 256) ? (15 - a) : a;     // complementary halves
  const int bh = id & 31;
  const int b = bh >> 4, h = bh & 15;
  const int tid = threadIdx.x;
  const int wave = tid >> 6, lane = tid & 63;
  const int l31 = lane & 31, hi = lane >> 5;

  const unsigned short* Qg = qb + (size_t)bh * SEQ * HD;
  const unsigned short* Kg = kb + (size_t)bh * SEQ * HD;
  const unsigned short* Vg = vtb + (size_t)bh * HD * SEQ;
  const float C = 0.12751744155229827f;  // (1/sqrt(128)) * log2(e)

  const int krow = tid >> 4, kc = tid & 15;
  const int ksw = (kc ^ (krow & 7)) * 8;
  const int vrow = tid >> 3, vc = tid & 7;
  const int vsw = (vc ^ (vrow & 7)) * 8;

#define STAGE_T(KV0, BUF)                                                      \
  {                                                                            \
    const unsigned short* K_ = Kg + (size_t)(KV0)*HD;                          \
    const unsigned short* V_ = Vg + (KV0);                                     \
    _Pragma("unroll") for (int p = 0; p < 4; ++p) {                            \
      gl_lds16(K_ + (size_t)(p * 16 + krow) * HD + ksw,                        \
               &Kl[BUF][(p * 256 + tid) * 8]);                                 \
      gl_lds16(V_ + (size_t)(p * 32 + vrow) * SEQ + vsw,                       \
               &Vl[BUF][(p * 256 + tid) * 8]);                                 \
    }                                                                          \
  }

  const int q0 = x * 128;
  const int nt = 2 * x + 2;
  const int qw = q0 + wave * 32 + l31;   // this lane's q-row

  bf16x8 qf[8];
#pragma unroll
  for (int ks = 0; ks < 8; ++ks)
    qf[ks] = *(const bf16x8*)&Qg[(size_t)qw * HD + ks * 16 + hi * 8];

  f32x16 oacc[4] = {};   // [dblk]; lane: col d = dblk*32+l31, row q = crow(r,hi)
  float m_run = -1e30f, l_run = 0.f;

  STAGE_T(0, 0);

  for (int t = 0; t < nt; ++t) {
    const int cur = t & 1;
    if (t + 1 < nt) {
      STAGE_T((t + 1) * 64, cur ^ 1);
      asm volatile("s_waitcnt vmcnt(8)" ::: "memory");
    } else {
      asm volatile("s_waitcnt vmcnt(0)" ::: "memory");
    }
    __builtin_amdgcn_s_barrier();

    // ---- S^T = K . Q^T : s0 = kv rows [0,32), s1 = [32,64); col q = l31 ----
    f32x16 s0 = {}, s1 = {};
    __builtin_amdgcn_s_setprio(1);
#pragma unroll
    for (int ks = 0; ks < 8; ++ks) {
      const int cch = ((2 * ks + hi) ^ (l31 & 7)) * 8;
      bf16x8 k0 = *(const bf16x8*)&Kl[cur][l31 * 128 + cch];
      bf16x8 k1 = *(const bf16x8*)&Kl[cur][(32 + l31) * 128 + cch];
      s0 = __builtin_amdgcn_mfma_f32_32x32x16_bf16(k0, qf[ks], s0, 0, 0, 0);
      s1 = __builtin_amdgcn_mfma_f32_32x32x16_bf16(k1, qf[ks], s1, 0, 0, 0);
    }
    __builtin_amdgcn_s_setprio(0);

    if (t >= nt - 2) {  // diagonal tiles: causal mask
      const int kv0 = t * 64;
#pragma unroll
      for (int r = 0; r < 16; ++r) {
        const int crow = (r & 3) + 8 * (r >> 2) + 4 * hi;
        if (kv0 + crow > qw) s0[r] = -1e30f;
        if (kv0 + 32 + crow > qw) s1[r] = -1e30f;
      }
    }

    // ---- in-lane row max + one cross-half combine ----
    float vm = -1e30f;
#pragma unroll
    for (int r = 0; r < 16; ++r) vm = fmaxf(vm, fmaxf(s0[r], s1[r]));
    vm = fmaxf(vm, __shfl_xor(vm, 32));

    // ---- defer-max (T13) ----
    if (__any(vm - m_run > 60.0f)) {
      const float nm = fmaxf(m_run, vm);
      const float pfac = exp2f((m_run - nm) * C);
#pragma unroll
      for (int r = 0; r < 16; ++r) {
        const int crow = (r & 3) + 8 * (r >> 2) + 4 * hi;
        const float f = __shfl(pfac, crow);
#pragma unroll
        for (int db = 0; db < 4; ++db) oacc[db][r] *= f;
      }
      l_run *= pfac;
      m_run = nm;
    }
    const float mC = m_run * C;

    // ---- exp + in-lane sum + one combine ----
    float ss = 0.f;
#pragma unroll
    for (int r = 0; r < 16; ++r) {
      s0[r] = exp2f(s0[r] * C - mC); ss += s0[r];
      s1[r] = exp2f(s1[r] * C - mC); ss += s1[r];
    }
    ss += __shfl_xor(ss, 32);
    l_run += ss;

    // ---- pack P (cvt_pk) + half-exchange -> PV A-frags (8 shfls) ----
    unsigned u[16];
#pragma unroll
    for (int i = 0; i < 8; ++i) {
      u[i] = cvt_pk_bf16(s0[2 * i], s0[2 * i + 1]);
      u[8 + i] = cvt_pk_bf16(s1[2 * i], s1[2 * i + 1]);
    }

    bf16x8 pf[4];
#pragma unroll
    for (int kb2 = 0; kb2 < 2; ++kb2) {
      const int o = kb2 * 8;
      unsigned a1 = hi ? u[o + 0] : u[o + 2];
      unsigned a2 = hi ? u[o + 1] : u[o + 3];
      unsigned a3 = hi ? u[o + 4] : u[o + 6];
      unsigned a4 = hi ? u[o + 5] : u[o + 7];
      unsigned t1 = (unsigned)__shfl_xor((int)a1, 32);
      unsigned t2 = (unsigned)__shfl_xor((int)a2, 32);
      unsigned t3 = (unsigned)__shfl_xor((int)a3, 32);
      unsigned t4 = (unsigned)__shfl_xor((int)a4, 32);
      u32x4 w0, w1;
      w0[0] = hi ? t1 : u[o + 0];
      w0[1] = hi ? t2 : u[o + 1];
      w0[2] = hi ? u[o + 2] : t1;
      w0[3] = hi ? u[o + 3] : t2;
      w1[0] = hi ? t3 : u[o + 4];
      w1[1] = hi ? t4 : u[o + 5];
      w1[2] = hi ? u[o + 6] : t3;
      w1[3] = hi ? u[o + 7] : t4;
      pf[kb2 * 2 + 0] = __builtin_bit_cast(bf16x8, w0);
      pf[kb2 * 2 + 1] = __builtin_bit_cast(bf16x8, w1);
    }

    // ---- O += P . V ----
    __builtin_amdgcn_s_setprio(1);
#pragma unroll
    for (int db = 0; db < 4; ++db) {
#pragma unroll
      for (int sl = 0; sl < 4; ++sl) {
        bf16x8 vf = *(const bf16x8*)&Vl[cur][(db * 32 + l31) * 64 +
                                            (((2 * sl + hi) ^ (l31 & 7)) * 8)];
        oacc[db] = __builtin_amdgcn_mfma_f32_32x32x16_bf16(pf[sl], vf, oacc[db], 0, 0, 0);
      }
    }
    __builtin_amdgcn_s_setprio(0);
    __builtin_amdgcn_s_barrier();
  }

  // ---- normalize + store fp32 ----
#pragma unroll
  for (int r = 0; r < 16; ++r) {
    const int crow = (r & 3) + 8 * (r >> 2) + 4 * hi;
    const float li = 1.0f / __shfl(l_run, crow);
    const int q = q0 + wave * 32 + crow;
    float* orow = out + ((size_t)b * SEQ + q) * DM + h * HD;
#pragma unroll
    for (int db = 0; db < 4; ++db)
      orow[db * 32 + l31] = oacc[db][r] * li;
  }
}

// ---------------- launcher ----------------
extern "C" void kernel_launch(void* const* d_in, const int* in_sizes, int n_in,
                              void* d_out, int out_size, void* d_ws, size_t ws_size,
                              hipStream_t stream) {
  const float* x  = (const float*)d_in[0];
  const float* Wq = (const float*)d_in[1];
  const float* Wk = (const float*)d_in[2];
  const float* Wv = (const float*)d_in[3];
  float* out = (float*)d_out;
  char* ws = (char*)d_ws;

  unsigned short* xb  = (unsigned short*)(ws);              // 4096x2048 bf16   (16 MB)
  unsigned short* wt  = (unsigned short*)(ws + 16777216);   // 3x 2048x2048 bf16 (24 MB)
  unsigned short* qb  = (unsigned short*)(ws + 41943040);   // [32][2048][128]  (16 MB)
  unsigned short* kb  = (unsigned short*)(ws + 58720256);   // [32][2048][128]  (16 MB)
  unsigned short* vtb = (unsigned short*)(ws + 75497472);   // [32][128][2048]  (16 MB)

  k_cvt_x<<<4096, 256, 0, stream>>>(x, xb);
  dim3 gw(32, 32, 3);
  k_cvt_w<<<gw, 256, 0, stream>>>(Wq, Wk, Wv, wt);
  k_qkv<<<256, 512, 0, stream>>>(xb, wt, qb, kb, vtb);
  k_attn<<<512, 256, 0, stream>>>(qb, kb, vtb, out);
}